// Round 1
// baseline (10768.684 us; speedup 1.0000x reference)
//
#include <hip/hip_runtime.h>
#include <math.h>

// Problem constants
constexpr int kH   = 64;    // state dim
constexpr int kP   = 4;     // FFT coeffs kept
constexpr int kN   = 16;    // noise dim
constexpr int kD   = 8;     // readout dim
constexpr int kT   = 64;    // timesteps
constexpr int kWd  = 512;   // MLP width
constexpr int kB   = 2048;  // batch
constexpr int kDIN = 1 + kH + kP * kH;  // 321
constexpr int kKP  = 336;   // K padded to multiple of 16
constexpr int kBH  = kB * kH;           // 131072

struct GArg {
    const float* A; const float* W; const float* bias; float* C;
    int N, K, lda, ldc, act;   // act: 0=relu, 1=tanh
};

// ---------------- weight prep: combined padded layer-1 weight [336 x 1024] ----
__global__ __launch_bounds__(256) void prep_w0(const float* __restrict__ fW0,
                                               const float* __restrict__ gW0,
                                               const float* __restrict__ fb0,
                                               const float* __restrict__ gb0,
                                               float* __restrict__ W0c,
                                               float* __restrict__ b0c) {
    int idx = blockIdx.x * 256 + threadIdx.x;
    if (idx < kKP * 1024) {
        int r = idx >> 10, c = idx & 1023;
        float v = 0.f;
        if (r < kDIN) v = (c < kWd) ? fW0[r * kWd + c] : gW0[r * kWd + (c - kWd)];
        W0c[idx] = v;
    }
    if (idx < 1024) b0c[idx] = (idx < kWd) ? fb0[idx] : gb0[idx - kWd];
}

// ---------------- init: hist[0] = 1, tx pad cols zero ------------------------
__global__ __launch_bounds__(256) void init_k(float* __restrict__ hist, float* __restrict__ tx) {
    int idx = blockIdx.x * 256 + threadIdx.x;
    if (idx < kBH) hist[idx] = 1.0f;
    if (idx < kB * (kKP - kDIN)) {
        int b = idx / (kKP - kDIN), c = idx % (kKP - kDIN);
        tx[(size_t)b * kKP + kDIN + c] = 0.f;
    }
}

// ---------------- build tx = [t | x | rfft-real feats] -----------------------
__global__ __launch_bounds__(256) void build_tx(const float* __restrict__ hist,
                                                float* __restrict__ tx, int k) {
    const int L = k + 1;
    __shared__ float ctab[kT * kP];  // cos(2*pi*p*j/L)/sqrt(L)
    int tid = threadIdx.x;
    float invs = rsqrtf((float)L);
    for (int i = tid; i < L * kP; i += 256) {
        int j = i >> 2, p = i & 3;
        float ang = 6.283185307179586f * (float)(p * j) / (float)L;
        ctab[i] = cosf(ang) * invs;
    }
    __syncthreads();
    int idx = blockIdx.x * 256 + tid;         // over B*H
    int b = idx >> 6, h = idx & 63;
    const float* hp = hist + (size_t)b * kH + h;
    float a0 = 0.f, a1 = 0.f, a2 = 0.f, a3 = 0.f;
    for (int j = 0; j < L; ++j) {
        float x = hp[(size_t)j * kBH];
        a0 += x * ctab[j * 4 + 0];
        a1 += x * ctab[j * 4 + 1];
        a2 += x * ctab[j * 4 + 2];
        a3 += x * ctab[j * 4 + 3];
    }
    // rfft of length L has floor(L/2)+1 coeffs: coeff p present iff 2p <= L
    if (2 * 1 > L) a1 = 0.f;
    if (2 * 2 > L) a2 = 0.f;
    if (2 * 3 > L) a3 = 0.f;
    float* txr = tx + (size_t)b * kKP;
    txr[1 + kH + 0 * kH + h] = a0;
    txr[1 + kH + 1 * kH + h] = a1;
    txr[1 + kH + 2 * kH + h] = a2;
    txr[1 + kH + 3 * kH + h] = a3;
    txr[1 + h] = hp[(size_t)k * kBH];         // curr_x
    if (h == 0) txr[0] = (float)k;            // curr_t (dt=1, no clamp for k<=62)
}

// ---------------- tiled fp32 GEMM, dual-branch via blockIdx.z ----------------
__global__ __launch_bounds__(256) void gemm_dual(GArg g0, GArg g1) {
    GArg g = (blockIdx.z == 0) ? g0 : g1;
    int n0 = blockIdx.y * 64;
    if (n0 >= g.N) return;
    int m0 = blockIdx.x * 64;

    __shared__ float As[16][68];  // transposed A tile: As[k][m], stride 68 keeps 16B align
    __shared__ float Bs[16][64];

    int tid  = threadIdx.x;
    int arow = tid >> 2, acol = (tid & 3) << 2;   // A tile loads
    int brow = tid >> 4, bcol = (tid & 15) << 2;  // B tile loads
    int tm   = (tid >> 4) << 2, tn = (tid & 15) << 2;

    float acc[4][4] = {};
    const float* Aptr = g.A + (size_t)(m0 + arow) * g.lda + acol;
    const float* Wptr = g.W + (size_t)brow * g.N + n0 + bcol;

    for (int k0 = 0; k0 < g.K; k0 += 16) {
        float4 av = *(const float4*)(Aptr + k0);
        float4 bv = *(const float4*)(Wptr + (size_t)k0 * g.N);
        __syncthreads();
        As[acol + 0][arow] = av.x;
        As[acol + 1][arow] = av.y;
        As[acol + 2][arow] = av.z;
        As[acol + 3][arow] = av.w;
        *(float4*)&Bs[brow][bcol] = bv;
        __syncthreads();
#pragma unroll
        for (int kk = 0; kk < 16; ++kk) {
            float4 a = *(const float4*)&As[kk][tm];
            float4 b = *(const float4*)&Bs[kk][tn];
            acc[0][0] += a.x * b.x; acc[0][1] += a.x * b.y; acc[0][2] += a.x * b.z; acc[0][3] += a.x * b.w;
            acc[1][0] += a.y * b.x; acc[1][1] += a.y * b.y; acc[1][2] += a.y * b.z; acc[1][3] += a.y * b.w;
            acc[2][0] += a.z * b.x; acc[2][1] += a.z * b.y; acc[2][2] += a.z * b.z; acc[2][3] += a.z * b.w;
            acc[3][0] += a.w * b.x; acc[3][1] += a.w * b.y; acc[3][2] += a.w * b.z; acc[3][3] += a.w * b.w;
        }
    }

    float4 bias4 = *(const float4*)(g.bias + n0 + tn);
#pragma unroll
    for (int i = 0; i < 4; ++i) {
        float r0 = acc[i][0] + bias4.x;
        float r1 = acc[i][1] + bias4.y;
        float r2 = acc[i][2] + bias4.z;
        float r3 = acc[i][3] + bias4.w;
        if (g.act == 0) {
            r0 = fmaxf(r0, 0.f); r1 = fmaxf(r1, 0.f); r2 = fmaxf(r2, 0.f); r3 = fmaxf(r3, 0.f);
        } else {
            r0 = tanhf(r0); r1 = tanhf(r1); r2 = tanhf(r2); r3 = tanhf(r3);
        }
        float4 o; o.x = r0; o.y = r1; o.z = r2; o.w = r3;
        *(float4*)(g.C + (size_t)(m0 + tm + i) * g.ldc + n0 + tn) = o;
    }
}

// ---------------- state update: x += drift + diff @ db -----------------------
__global__ __launch_bounds__(256) void update_k(float* __restrict__ hist,
                                                const float* __restrict__ drift,
                                                const float* __restrict__ diffb,
                                                const float* __restrict__ dbt, int k) {
    int idx = blockIdx.x * 256 + threadIdx.x;  // B*H
    int b = idx >> 6, h = idx & 63;
    float s = hist[(size_t)k * kBH + idx] + drift[idx];
    const float* dr = diffb + (size_t)b * (kH * kN) + h * kN;
    const float* wr = dbt + (size_t)k * kB * kN + b * kN;
#pragma unroll
    for (int n = 0; n < kN; ++n) s += dr[n] * wr[n];
    hist[(size_t)(k + 1) * kBH + idx] = s;
}

// ---------------- readout: out = [ts | hist @ rW + rb] -----------------------
__global__ __launch_bounds__(256) void readout_k(const float* __restrict__ hist,
                                                 const float* __restrict__ rW,
                                                 const float* __restrict__ rb,
                                                 const float* __restrict__ ts,
                                                 float* __restrict__ out) {
    __shared__ float sW[kH * kD];
    __shared__ float sb[kD];
    __shared__ float sts[kT];
    int tid = threadIdx.x;
    sW[tid] = rW[tid];
    sW[tid + 256] = rW[tid + 256];
    if (tid < kD) sb[tid] = rb[tid];
    if (tid < kT) sts[tid] = ts[tid];
    __syncthreads();
    int idx = blockIdx.x * 256 + tid;  // B*T
    int t = idx & (kT - 1), b = idx >> 6;
    const float* xr = hist + (size_t)t * kBH + (size_t)b * kH;
    float acc[kD];
#pragma unroll
    for (int d = 0; d < kD; ++d) acc[d] = sb[d];
    for (int h = 0; h < kH; ++h) {
        float x = xr[h];
#pragma unroll
        for (int d = 0; d < kD; ++d) acc[d] += x * sW[h * kD + d];
    }
    float* o = out + (size_t)((size_t)b * kT + t) * (1 + kD);
    o[0] = sts[t];
#pragma unroll
    for (int d = 0; d < kD; ++d) o[1 + d] = acc[d];
}

extern "C" void kernel_launch(void* const* d_in, const int* in_sizes, int n_in,
                              void* d_out, int out_size, void* d_ws, size_t ws_size,
                              hipStream_t stream) {
    const float* fW0 = (const float*)d_in[0];  const float* fb0 = (const float*)d_in[1];
    const float* fW1 = (const float*)d_in[2];  const float* fb1 = (const float*)d_in[3];
    const float* fW2 = (const float*)d_in[4];  const float* fb2 = (const float*)d_in[5];
    const float* fW3 = (const float*)d_in[6];  const float* fb3 = (const float*)d_in[7];
    const float* gW0 = (const float*)d_in[8];  const float* gb0 = (const float*)d_in[9];
    const float* gW1 = (const float*)d_in[10]; const float* gb1 = (const float*)d_in[11];
    const float* gW2 = (const float*)d_in[12]; const float* gb2 = (const float*)d_in[13];
    const float* gW3 = (const float*)d_in[14]; const float* gb3 = (const float*)d_in[15];
    const float* rW  = (const float*)d_in[16]; const float* rb  = (const float*)d_in[17];
    const float* ts  = (const float*)d_in[18]; const float* dbt = (const float*)d_in[19];
    float* out = (float*)d_out;

    float* ws    = (float*)d_ws;
    float* hist  = ws;                          // T*B*H     = 8388608
    float* tx    = hist  + (size_t)kT * kBH;    // B*336     = 688128
    float* buf1  = tx    + (size_t)kB * kKP;    // B*1024    = 2097152
    float* buf2  = buf1  + (size_t)kB * 1024;   // B*1024
    float* drift = buf2  + (size_t)kB * 1024;   // B*64
    float* diffb = drift + (size_t)kB * kH;     // B*1024
    float* W0c   = diffb + (size_t)kB * 1024;   // 336*1024  = 344064
    float* b0c   = W0c   + (size_t)kKP * 1024;  // 1024

    prep_w0<<<dim3((kKP * 1024 + 255) / 256), dim3(256), 0, stream>>>(fW0, gW0, fb0, gb0, W0c, b0c);
    init_k<<<dim3(kBH / 256), dim3(256), 0, stream>>>(hist, tx);

    for (int k = 0; k < kT - 1; ++k) {
        build_tx<<<dim3(kBH / 256), dim3(256), 0, stream>>>(hist, tx, k);

        GArg l1{tx, W0c, b0c, buf1, 1024, kKP, kKP, 1024, 0};
        gemm_dual<<<dim3(32, 16, 1), dim3(256), 0, stream>>>(l1, l1);

        GArg f2{buf1, fW1, fb1, buf2, kWd, kWd, 1024, 1024, 0};
        GArg g2{buf1 + kWd, gW1, gb1, buf2 + kWd, kWd, kWd, 1024, 1024, 0};
        gemm_dual<<<dim3(32, 8, 2), dim3(256), 0, stream>>>(f2, g2);

        GArg f3{buf2, fW2, fb2, buf1, kWd, kWd, 1024, 1024, 0};
        GArg g3{buf2 + kWd, gW2, gb2, buf1 + kWd, kWd, kWd, 1024, 1024, 0};
        gemm_dual<<<dim3(32, 8, 2), dim3(256), 0, stream>>>(f3, g3);

        GArg f4{buf1, fW3, fb3, drift, kH, kWd, 1024, kH, 1};
        GArg g4{buf1 + kWd, gW3, gb3, diffb, kH * kN, kWd, 1024, kH * kN, 1};
        gemm_dual<<<dim3(32, 16, 2), dim3(256), 0, stream>>>(f4, g4);

        update_k<<<dim3(kBH / 256), dim3(256), 0, stream>>>(hist, drift, diffb, dbt, k);
    }

    readout_k<<<dim3(kB * kT / 256), dim3(256), 0, stream>>>(hist, rW, rb, ts, out);
}

// Round 2
// 5758.595 us; speedup vs baseline: 1.8700x; 1.8700x over previous
//
#include <hip/hip_runtime.h>
#include <math.h>

// Problem constants
constexpr int kH   = 64;
constexpr int kP   = 4;
constexpr int kN   = 16;
constexpr int kD   = 8;
constexpr int kT   = 64;
constexpr int kWd  = 512;
constexpr int kB   = 2048;
constexpr int kDIN = 1 + kH + kP * kH;  // 321
constexpr int kKP  = 352;               // K padded to multiple of 32
constexpr int kBH  = kB * kH;           // 131072

typedef __attribute__((ext_vector_type(8))) short short8;
typedef __attribute__((ext_vector_type(4))) float f32x4;

// ---- bf16 helpers -----------------------------------------------------------
__device__ __forceinline__ short f2bf(float x) {
    union { float f; unsigned u; } v; v.f = x;
    unsigned r = (v.u + 0x7FFFu + ((v.u >> 16) & 1u)) >> 16;
    return (short)r;
}
__device__ __forceinline__ float bf2f(short h) {
    union { unsigned u; float f; } v; v.u = ((unsigned)(unsigned short)h) << 16;
    return v.f;
}
__device__ __forceinline__ void put2(short* th, short* tl, int off, float v) {
    short hi = f2bf(v);
    th[off] = hi;
    tl[off] = f2bf(v - bf2f(hi));
}

// ---- async global->LDS 16B --------------------------------------------------
__device__ __forceinline__ void gload16(const short* g, short* l) {
    __builtin_amdgcn_global_load_lds(
        (const __attribute__((address_space(1))) unsigned int*)g,
        (__attribute__((address_space(3))) unsigned int*)l, 16, 0, 0);
}

// ---- weight transpose to bf16 [N][K] with padding ---------------------------
__global__ __launch_bounds__(256) void transpose_bf16(const float* __restrict__ W,
                                                      short* __restrict__ Wt,
                                                      int K, int N, int Kp, int Np) {
    int idx = blockIdx.x * 256 + threadIdx.x;
    if (idx >= Kp * Np) return;
    int n = idx / Kp, kk = idx % Kp;
    float v = (kk < K && n < N) ? W[(size_t)kk * N + n] : 0.f;
    Wt[idx] = f2bf(v);
}

__global__ __launch_bounds__(256) void prep_bias(const float* __restrict__ fb0,
                                                 const float* __restrict__ gb0,
                                                 const float* __restrict__ fb3,
                                                 float* __restrict__ b0c,
                                                 float* __restrict__ fb3p) {
    int i = blockIdx.x * 256 + threadIdx.x;
    if (i < 1024) b0c[i] = (i < kWd) ? fb0[i] : gb0[i - kWd];
    if (i < 128)  fb3p[i] = (i < kH) ? fb3[i] : 0.f;
}

// ---- init: hist[0]=1, tx pad cols zero --------------------------------------
__global__ __launch_bounds__(256) void init_k(float* __restrict__ hist,
                                              short* __restrict__ txh,
                                              short* __restrict__ txl) {
    int idx = blockIdx.x * 256 + threadIdx.x;
    if (idx < kBH) hist[idx] = 1.0f;
    if (idx < kB * (kKP - kDIN)) {
        int b = idx / (kKP - kDIN), c = idx % (kKP - kDIN);
        txh[(size_t)b * kKP + kDIN + c] = 0;
        txl[(size_t)b * kKP + kDIN + c] = 0;
    }
}

// ---- fused: state update (step k) + build tx features -----------------------
__global__ __launch_bounds__(256) void step_pre(float* __restrict__ hist,
                                                const float* __restrict__ drift,
                                                const float* __restrict__ diffb,
                                                const float* __restrict__ dbt,
                                                short* __restrict__ txh,
                                                short* __restrict__ txl, int k) {
    const int L = k + 1;
    __shared__ float ctab[kT * kP];
    int tid = threadIdx.x;
    float invs = rsqrtf((float)L);
    for (int i = tid; i < L * kP; i += 256) {
        int j = i >> 2, p = i & 3;
        ctab[i] = cosf(6.283185307179586f * (float)(p * j) / (float)L) * invs;
    }
    __syncthreads();
    int idx = blockIdx.x * 256 + tid;
    int b = idx >> 6, h = idx & 63;
    float xk;
    if (k == 0) {
        xk = 1.0f;
    } else {
        xk = hist[(size_t)(k - 1) * kBH + idx] + drift[idx];
        const float* dr = diffb + (size_t)b * (kH * kN) + h * kN;
        const float* wr = dbt + (size_t)(k - 1) * kB * kN + b * kN;
#pragma unroll
        for (int n = 0; n < kN; ++n) xk += dr[n] * wr[n];
        hist[(size_t)k * kBH + idx] = xk;
    }
    const float* hp = hist + (size_t)b * kH + h;
    float a0 = 0.f, a1 = 0.f, a2 = 0.f, a3 = 0.f;
    for (int j = 0; j < k; ++j) {
        float x = hp[(size_t)j * kBH];
        a0 += x * ctab[j * 4 + 0];
        a1 += x * ctab[j * 4 + 1];
        a2 += x * ctab[j * 4 + 2];
        a3 += x * ctab[j * 4 + 3];
    }
    a0 += xk * ctab[k * 4 + 0];
    a1 += xk * ctab[k * 4 + 1];
    a2 += xk * ctab[k * 4 + 2];
    a3 += xk * ctab[k * 4 + 3];
    if (L < 2) a1 = 0.f;
    if (L < 4) a2 = 0.f;
    if (L < 6) a3 = 0.f;
    short* th = txh + (size_t)b * kKP;
    short* tl = txl + (size_t)b * kKP;
    put2(th, tl, 1 + kH + 0 * kH + h, a0);
    put2(th, tl, 1 + kH + 1 * kH + h, a1);
    put2(th, tl, 1 + kH + 2 * kH + h, a2);
    put2(th, tl, 1 + kH + 3 * kH + h, a3);
    put2(th, tl, 1 + h, xk);
    if (h == 0) put2(th, tl, 0, (float)k);
}

// ---- MFMA GEMM: C = act(A @ Wt^T + bias), A = Ah + Al (split bf16) ----------
struct MArg {
    const short* Ah; const short* Al;   // [2048 x lda] bf16 pair
    const short* Bt;                    // [N x K] bf16 (transposed weights)
    const float* bias;                  // [>=N]
    short* Ch; short* Cl;               // bf16 outputs (act=0)
    float* Cf;                          // fp32 output (act=1)
    int N, K, lda, ldc, act, Nw;
};

__global__ __launch_bounds__(128) void gemm_mfma(MArg g0, MArg g1) {
    MArg g = blockIdx.z ? g1 : g0;
    const int n0 = blockIdx.y * 128;
    if (n0 >= g.N) return;
    const int m0 = blockIdx.x * 64;

    __shared__ __align__(16) short sAh[64 * 32];
    __shared__ __align__(16) short sAl[64 * 32];
    __shared__ __align__(16) short sB[128 * 32];

    const int tid = threadIdx.x;
    const int lane = tid & 63;
    const int w = tid >> 6;  // wave 0/1 -> n-half

    f32x4 acc[4][4] = {};

    const int sr = tid >> 2;          // 0..31
    const int sc = (tid & 3) * 8;     // bf16 col within 32
    const short* gAh = g.Ah + (size_t)(m0 + sr) * g.lda + sc;
    const short* gAl = g.Al + (size_t)(m0 + sr) * g.lda + sc;
    const short* gB  = g.Bt + (size_t)(n0 + sr) * g.K + sc;

    for (int k0 = 0; k0 < g.K; k0 += 32) {
        __syncthreads();
        gload16(gAh + k0,                       &sAh[sr * 32 + sc]);
        gload16(gAh + k0 + (size_t)32 * g.lda,  &sAh[(sr + 32) * 32 + sc]);
        gload16(gAl + k0,                       &sAl[sr * 32 + sc]);
        gload16(gAl + k0 + (size_t)32 * g.lda,  &sAl[(sr + 32) * 32 + sc]);
        gload16(gB + k0,                        &sB[sr * 32 + sc]);
        gload16(gB + k0 + (size_t)32 * g.K,     &sB[(sr + 32) * 32 + sc]);
        gload16(gB + k0 + (size_t)64 * g.K,     &sB[(sr + 64) * 32 + sc]);
        gload16(gB + k0 + (size_t)96 * g.K,     &sB[(sr + 96) * 32 + sc]);
        __syncthreads();

        const int fr = lane & 15, kb = (lane >> 4) * 8;
        short8 bfr[4], ah[4], al[4];
#pragma unroll
        for (int j = 0; j < 4; ++j)
            bfr[j] = *(const short8*)&sB[(w * 64 + j * 16 + fr) * 32 + kb];
#pragma unroll
        for (int i = 0; i < 4; ++i) {
            ah[i] = *(const short8*)&sAh[(i * 16 + fr) * 32 + kb];
            al[i] = *(const short8*)&sAl[(i * 16 + fr) * 32 + kb];
        }
#pragma unroll
        for (int i = 0; i < 4; ++i)
#pragma unroll
            for (int j = 0; j < 4; ++j) {
                acc[i][j] = __builtin_amdgcn_mfma_f32_16x16x32_bf16(ah[i], bfr[j], acc[i][j], 0, 0, 0);
                acc[i][j] = __builtin_amdgcn_mfma_f32_16x16x32_bf16(al[i], bfr[j], acc[i][j], 0, 0, 0);
            }
    }

    const int fr = lane & 15, rq = (lane >> 4) * 4;
#pragma unroll
    for (int j = 0; j < 4; ++j) {
        int n = n0 + w * 64 + j * 16 + fr;
        if (n >= g.Nw) continue;
        float bias = g.bias[n];
#pragma unroll
        for (int i = 0; i < 4; ++i) {
#pragma unroll
            for (int r = 0; r < 4; ++r) {
                int m = m0 + i * 16 + rq + r;
                float v = acc[i][j][r] + bias;
                if (g.act == 0) {
                    v = fmaxf(v, 0.f);
                    short hi = f2bf(v);
                    g.Ch[(size_t)m * g.ldc + n] = hi;
                    g.Cl[(size_t)m * g.ldc + n] = f2bf(v - bf2f(hi));
                } else {
                    g.Cf[(size_t)m * g.ldc + n] = tanhf(v);
                }
            }
        }
    }
}

// ---- final state update (k = T-1) -------------------------------------------
__global__ __launch_bounds__(256) void update_k(float* __restrict__ hist,
                                                const float* __restrict__ drift,
                                                const float* __restrict__ diffb,
                                                const float* __restrict__ dbt, int k) {
    int idx = blockIdx.x * 256 + threadIdx.x;
    int b = idx >> 6, h = idx & 63;
    float s = hist[(size_t)k * kBH + idx] + drift[idx];
    const float* dr = diffb + (size_t)b * (kH * kN) + h * kN;
    const float* wr = dbt + (size_t)k * kB * kN + b * kN;
#pragma unroll
    for (int n = 0; n < kN; ++n) s += dr[n] * wr[n];
    hist[(size_t)(k + 1) * kBH + idx] = s;
}

// ---- readout ----------------------------------------------------------------
__global__ __launch_bounds__(256) void readout_k(const float* __restrict__ hist,
                                                 const float* __restrict__ rW,
                                                 const float* __restrict__ rb,
                                                 const float* __restrict__ ts,
                                                 float* __restrict__ out) {
    __shared__ float sW[kH * kD];
    __shared__ float sb[kD];
    __shared__ float sts[kT];
    int tid = threadIdx.x;
    sW[tid] = rW[tid];
    sW[tid + 256] = rW[tid + 256];
    if (tid < kD) sb[tid] = rb[tid];
    if (tid < kT) sts[tid] = ts[tid];
    __syncthreads();
    int idx = blockIdx.x * 256 + tid;
    int t = idx & (kT - 1), b = idx >> 6;
    const float* xr = hist + (size_t)t * kBH + (size_t)b * kH;
    float acc[kD];
#pragma unroll
    for (int d = 0; d < kD; ++d) acc[d] = sb[d];
    for (int h = 0; h < kH; ++h) {
        float x = xr[h];
#pragma unroll
        for (int d = 0; d < kD; ++d) acc[d] += x * sW[h * kD + d];
    }
    float* o = out + (size_t)((size_t)b * kT + t) * (1 + kD);
    o[0] = sts[t];
#pragma unroll
    for (int d = 0; d < kD; ++d) o[1 + d] = acc[d];
}

extern "C" void kernel_launch(void* const* d_in, const int* in_sizes, int n_in,
                              void* d_out, int out_size, void* d_ws, size_t ws_size,
                              hipStream_t stream) {
    const float* fW0 = (const float*)d_in[0];  const float* fb0 = (const float*)d_in[1];
    const float* fW1 = (const float*)d_in[2];  const float* fb1 = (const float*)d_in[3];
    const float* fW2 = (const float*)d_in[4];  const float* fb2 = (const float*)d_in[5];
    const float* fW3 = (const float*)d_in[6];  const float* fb3 = (const float*)d_in[7];
    const float* gW0 = (const float*)d_in[8];  const float* gb0 = (const float*)d_in[9];
    const float* gW1 = (const float*)d_in[10]; const float* gb1 = (const float*)d_in[11];
    const float* gW2 = (const float*)d_in[12]; const float* gb2 = (const float*)d_in[13];
    const float* gW3 = (const float*)d_in[14]; const float* gb3 = (const float*)d_in[15];
    const float* rW  = (const float*)d_in[16]; const float* rb  = (const float*)d_in[17];
    const float* ts  = (const float*)d_in[18]; const float* dbt = (const float*)d_in[19];
    float* out = (float*)d_out;

    // workspace carve (bytes, all 16B aligned). Total ~57.7 MB.
    char* p = (char*)d_ws;
    float* hist = (float*)p;            p += (size_t)kT * kBH * 4;        // 33.55 MB
    float* drift = (float*)p;           p += (size_t)kBH * 4;             // 0.52 MB
    float* b0c = (float*)p;             p += 1024 * 4;
    float* fb3p = (float*)p;            p += 128 * 4;
    short* txh = (short*)p;             p += (size_t)kB * kKP * 2;        // 1.44 MB
    short* txl = (short*)p;             p += (size_t)kB * kKP * 2;
    short* b1h = (short*)p;             p += (size_t)kB * 1024 * 2;       // 4 MB
    short* b1l = (short*)p;             p += (size_t)kB * 1024 * 2;
    short* b2h = (short*)p;             p += (size_t)kB * 1024 * 2;
    short* b2l = (short*)p;             p += (size_t)kB * 1024 * 2;
    short* W0t = (short*)p;             p += (size_t)1024 * kKP * 2;      // 0.72 MB
    short* fW1t = (short*)p;            p += (size_t)512 * 512 * 2;
    short* gW1t = (short*)p;            p += (size_t)512 * 512 * 2;
    short* fW2t = (short*)p;            p += (size_t)512 * 512 * 2;
    short* gW2t = (short*)p;            p += (size_t)512 * 512 * 2;
    short* fW3t = (short*)p;            p += (size_t)128 * 512 * 2;
    short* gW3t = (short*)p;            p += (size_t)1024 * 512 * 2;
    // diffb aliases buf2 (dead between L3 of step k and L2 of step k+1)
    float* diffb = (float*)b2h;

    // ---- one-time (per call) prep ----
    auto tgrid = [](int n) { return dim3((n + 255) / 256); };
    transpose_bf16<<<tgrid(kKP * 512), 256, 0, stream>>>(fW0, W0t, kDIN, 512, kKP, 512);
    transpose_bf16<<<tgrid(kKP * 512), 256, 0, stream>>>(gW0, W0t + (size_t)512 * kKP, kDIN, 512, kKP, 512);
    transpose_bf16<<<tgrid(512 * 512), 256, 0, stream>>>(fW1, fW1t, 512, 512, 512, 512);
    transpose_bf16<<<tgrid(512 * 512), 256, 0, stream>>>(gW1, gW1t, 512, 512, 512, 512);
    transpose_bf16<<<tgrid(512 * 512), 256, 0, stream>>>(fW2, fW2t, 512, 512, 512, 512);
    transpose_bf16<<<tgrid(512 * 512), 256, 0, stream>>>(gW2, gW2t, 512, 512, 512, 512);
    transpose_bf16<<<tgrid(512 * 128), 256, 0, stream>>>(fW3, fW3t, 512, 64, 512, 128);
    transpose_bf16<<<tgrid(512 * 1024), 256, 0, stream>>>(gW3, gW3t, 512, 1024, 512, 1024);
    prep_bias<<<dim3(4), 256, 0, stream>>>(fb0, gb0, fb3, b0c, fb3p);
    init_k<<<dim3(kBH / 256), 256, 0, stream>>>(hist, txh, txl);

    for (int k = 0; k < kT - 1; ++k) {
        step_pre<<<dim3(kBH / 256), 256, 0, stream>>>(hist, drift, diffb, dbt, txh, txl, k);

        MArg l1{txh, txl, W0t, b0c, b1h, b1l, nullptr, 1024, kKP, kKP, 1024, 0, 1024};
        gemm_mfma<<<dim3(32, 8, 1), dim3(128), 0, stream>>>(l1, l1);

        MArg f2{b1h, b1l, fW1t, fb1, b2h, b2l, nullptr, 512, 512, 1024, 1024, 0, 512};
        MArg g2{b1h + 512, b1l + 512, gW1t, gb1, b2h + 512, b2l + 512, nullptr, 512, 512, 1024, 1024, 0, 512};
        gemm_mfma<<<dim3(32, 4, 2), dim3(128), 0, stream>>>(f2, g2);

        MArg f3{b2h, b2l, fW2t, fb2, b1h, b1l, nullptr, 512, 512, 1024, 1024, 0, 512};
        MArg g3{b2h + 512, b2l + 512, gW2t, gb2, b1h + 512, b1l + 512, nullptr, 512, 512, 1024, 1024, 0, 512};
        gemm_mfma<<<dim3(32, 4, 2), dim3(128), 0, stream>>>(f3, g3);

        MArg f4{b1h, b1l, fW3t, fb3p, nullptr, nullptr, drift, 128, 512, 1024, kH, 1, kH};
        MArg g4{b1h + 512, b1l + 512, gW3t, gb3, nullptr, nullptr, diffb, 1024, 512, 1024, 1024, 1, 1024};
        gemm_mfma<<<dim3(32, 8, 2), dim3(128), 0, stream>>>(f4, g4);
    }

    update_k<<<dim3(kBH / 256), 256, 0, stream>>>(hist, drift, diffb, dbt, kT - 2);
    readout_k<<<dim3(kB * kT / 256), 256, 0, stream>>>(hist, rW, rb, ts, out);
}

// Round 3
// 2942.743 us; speedup vs baseline: 3.6594x; 1.9569x over previous
//
#include <hip/hip_runtime.h>
#include <math.h>

// Problem constants
constexpr int kH   = 64;
constexpr int kP   = 4;
constexpr int kN   = 16;
constexpr int kD   = 8;
constexpr int kT   = 64;
constexpr int kWd  = 512;
constexpr int kB   = 2048;
constexpr int kDIN = 1 + kH + kP * kH;  // 321
constexpr int kKP  = 352;               // K padded to multiple of 32
constexpr int kBH  = kB * kH;           // 131072

typedef __attribute__((ext_vector_type(8))) short short8;
typedef __attribute__((ext_vector_type(4))) float f32x4;

// ---- bf16 helpers -----------------------------------------------------------
__device__ __forceinline__ short f2bf(float x) {
    union { float f; unsigned u; } v; v.f = x;
    unsigned r = (v.u + 0x7FFFu + ((v.u >> 16) & 1u)) >> 16;
    return (short)r;
}

// ---- async global->LDS 16B --------------------------------------------------
__device__ __forceinline__ void gload16(const short* g, short* l) {
    __builtin_amdgcn_global_load_lds(
        (const __attribute__((address_space(1))) unsigned int*)g,
        (__attribute__((address_space(3))) unsigned int*)l, 16, 0, 0);
}

// ---- weight transpose to bf16 [N][K] with padding ---------------------------
__global__ __launch_bounds__(256) void transpose_bf16(const float* __restrict__ W,
                                                      short* __restrict__ Wt,
                                                      int K, int N, int Kp, int Np) {
    int idx = blockIdx.x * 256 + threadIdx.x;
    if (idx >= Kp * Np) return;
    int n = idx / Kp, kk = idx % Kp;
    float v = (kk < K && n < N) ? W[(size_t)kk * N + n] : 0.f;
    Wt[idx] = f2bf(v);
}

__global__ __launch_bounds__(256) void prep_bias(const float* __restrict__ fb0,
                                                 const float* __restrict__ gb0,
                                                 float* __restrict__ b0c) {
    int i = blockIdx.x * 256 + threadIdx.x;
    if (i < 1024) b0c[i] = (i < kWd) ? fb0[i] : gb0[i - kWd];
}

// ---- init: hist[0]=1, tx pad cols zero --------------------------------------
__global__ __launch_bounds__(256) void init_k(float* __restrict__ hist,
                                              short* __restrict__ txh) {
    int idx = blockIdx.x * 256 + threadIdx.x;
    if (idx < kBH) hist[idx] = 1.0f;
    if (idx < kB * (kKP - kDIN)) {
        int b = idx / (kKP - kDIN), c = idx % (kKP - kDIN);
        txh[(size_t)b * kKP + kDIN + c] = 0;
    }
}

// ---- fused: state update (step k) + build tx features -----------------------
__global__ __launch_bounds__(256) void step_pre(float* __restrict__ hist,
                                                const float* __restrict__ drift,
                                                const float* __restrict__ diffb,
                                                const float* __restrict__ dbt,
                                                short* __restrict__ txh, int k) {
    const int L = k + 1;
    __shared__ float ctab[kT * kP];
    int tid = threadIdx.x;
    float invs = rsqrtf((float)L);
    for (int i = tid; i < L * kP; i += 256) {
        int j = i >> 2, p = i & 3;
        ctab[i] = cosf(6.283185307179586f * (float)(p * j) / (float)L) * invs;
    }
    __syncthreads();
    int idx = blockIdx.x * 256 + tid;
    int b = idx >> 6, h = idx & 63;
    float xk;
    if (k == 0) {
        xk = 1.0f;
    } else {
        xk = hist[(size_t)(k - 1) * kBH + idx] + drift[idx];
        const float* dr = diffb + (size_t)b * 1024 + h * kN;
        const float* wr = dbt + (size_t)(k - 1) * kB * kN + b * kN;
#pragma unroll
        for (int n = 0; n < kN; ++n) xk += dr[n] * wr[n];
        hist[(size_t)k * kBH + idx] = xk;
    }
    const float* hp = hist + (size_t)b * kH + h;
    float a0 = 0.f, a1 = 0.f, a2 = 0.f, a3 = 0.f;
    for (int j = 0; j < k; ++j) {
        float x = hp[(size_t)j * kBH];
        a0 += x * ctab[j * 4 + 0];
        a1 += x * ctab[j * 4 + 1];
        a2 += x * ctab[j * 4 + 2];
        a3 += x * ctab[j * 4 + 3];
    }
    a0 += xk * ctab[k * 4 + 0];
    a1 += xk * ctab[k * 4 + 1];
    a2 += xk * ctab[k * 4 + 2];
    a3 += xk * ctab[k * 4 + 3];
    if (L < 2) a1 = 0.f;
    if (L < 4) a2 = 0.f;
    if (L < 6) a3 = 0.f;
    short* th = txh + (size_t)b * kKP;
    th[1 + kH + 0 * kH + h] = f2bf(a0);
    th[1 + kH + 1 * kH + h] = f2bf(a1);
    th[1 + kH + 2 * kH + h] = f2bf(a2);
    th[1 + kH + 3 * kH + h] = f2bf(a3);
    th[1 + h] = f2bf(xk);
    if (h == 0) th[0] = f2bf((float)k);
}

// ---- MFMA GEMM: C = act(A @ Wt^T + bias) ------------------------------------
// 256 threads = 4 waves (2M x 2N), block tile 64x64, wave tile 32x32.
struct MArg {
    const short* A;                     // [2048 x lda] bf16
    const short* Bt;                    // [Np x K] bf16 (transposed weights)
    const float* bias;
    short* Cb;                          // bf16 out (act=0)
    float* Cf;                          // fp32 out (act=1)
    int K, lda, ldc, act, Nw;
};

__global__ __launch_bounds__(256) void gemm_mfma(MArg f, MArg g, int ysplit) {
    const int y = blockIdx.y;
    MArg a;
    int n0;
    if (y < ysplit) { a = f; n0 = y * 64; }
    else            { a = g; n0 = (y - ysplit) * 64; }
    const int m0 = blockIdx.x * 64;

    __shared__ __align__(16) short sA[64 * 32];
    __shared__ __align__(16) short sB[64 * 32];

    const int tid = threadIdx.x;
    const int lane = tid & 63;
    const int w = tid >> 6;                 // wave id 0..3
    const int wm = (w & 1) * 32;            // wave M offset
    const int wn = (w >> 1) * 32;           // wave N offset

    f32x4 acc[2][2] = {};

    const int sr = tid >> 2;                // 0..63 staging row
    const int sc = (tid & 3) * 8;           // bf16 col within 32
    const short* gA = a.A  + (size_t)(m0 + sr) * a.lda + sc;
    const short* gB = a.Bt + (size_t)(n0 + sr) * a.K + sc;

    for (int k0 = 0; k0 < a.K; k0 += 32) {
        __syncthreads();
        gload16(gA + k0, &sA[sr * 32 + sc]);
        gload16(gB + k0, &sB[sr * 32 + sc]);
        __syncthreads();

        const int fr = lane & 15, kb = (lane >> 4) * 8;
        short8 av[2], bv[2];
#pragma unroll
        for (int i = 0; i < 2; ++i) {
            av[i] = *(const short8*)&sA[(wm + i * 16 + fr) * 32 + kb];
            bv[i] = *(const short8*)&sB[(wn + i * 16 + fr) * 32 + kb];
        }
#pragma unroll
        for (int i = 0; i < 2; ++i)
#pragma unroll
            for (int j = 0; j < 2; ++j)
                acc[i][j] = __builtin_amdgcn_mfma_f32_16x16x32_bf16(av[i], bv[j], acc[i][j], 0, 0, 0);
    }

    const int fr = lane & 15, rq = (lane >> 4) * 4;
#pragma unroll
    for (int j = 0; j < 2; ++j) {
        int n = n0 + wn + j * 16 + fr;
        if (n >= a.Nw) continue;
        float bias = a.bias[n];
#pragma unroll
        for (int i = 0; i < 2; ++i) {
#pragma unroll
            for (int r = 0; r < 4; ++r) {
                int m = m0 + wm + i * 16 + rq + r;
                float v = acc[i][j][r] + bias;
                if (a.act == 0) {
                    a.Cb[(size_t)m * a.ldc + n] = f2bf(fmaxf(v, 0.f));
                } else {
                    a.Cf[(size_t)m * a.ldc + n] = tanhf(v);
                }
            }
        }
    }
}

// ---- final state update (k = T-1) -------------------------------------------
__global__ __launch_bounds__(256) void update_k(float* __restrict__ hist,
                                                const float* __restrict__ drift,
                                                const float* __restrict__ diffb,
                                                const float* __restrict__ dbt, int k) {
    int idx = blockIdx.x * 256 + threadIdx.x;
    int b = idx >> 6, h = idx & 63;
    float s = hist[(size_t)k * kBH + idx] + drift[idx];
    const float* dr = diffb + (size_t)b * 1024 + h * kN;
    const float* wr = dbt + (size_t)k * kB * kN + b * kN;
#pragma unroll
    for (int n = 0; n < kN; ++n) s += dr[n] * wr[n];
    hist[(size_t)(k + 1) * kBH + idx] = s;
}

// ---- readout ----------------------------------------------------------------
__global__ __launch_bounds__(256) void readout_k(const float* __restrict__ hist,
                                                 const float* __restrict__ rW,
                                                 const float* __restrict__ rb,
                                                 const float* __restrict__ ts,
                                                 float* __restrict__ out) {
    __shared__ float sW[kH * kD];
    __shared__ float sb[kD];
    __shared__ float sts[kT];
    int tid = threadIdx.x;
    sW[tid] = rW[tid];
    sW[tid + 256] = rW[tid + 256];
    if (tid < kD) sb[tid] = rb[tid];
    if (tid < kT) sts[tid] = ts[tid];
    __syncthreads();
    int idx = blockIdx.x * 256 + tid;
    int t = idx & (kT - 1), b = idx >> 6;
    const float* xr = hist + (size_t)t * kBH + (size_t)b * kH;
    float acc[kD];
#pragma unroll
    for (int d = 0; d < kD; ++d) acc[d] = sb[d];
    for (int h = 0; h < kH; ++h) {
        float x = xr[h];
#pragma unroll
        for (int d = 0; d < kD; ++d) acc[d] += x * sW[h * kD + d];
    }
    float* o = out + (size_t)((size_t)b * kT + t) * (1 + kD);
    o[0] = sts[t];
#pragma unroll
    for (int d = 0; d < kD; ++d) o[1 + d] = acc[d];
}

extern "C" void kernel_launch(void* const* d_in, const int* in_sizes, int n_in,
                              void* d_out, int out_size, void* d_ws, size_t ws_size,
                              hipStream_t stream) {
    const float* fW0 = (const float*)d_in[0];  const float* fb0 = (const float*)d_in[1];
    const float* fW1 = (const float*)d_in[2];  const float* fb1 = (const float*)d_in[3];
    const float* fW2 = (const float*)d_in[4];  const float* fb2 = (const float*)d_in[5];
    const float* fW3 = (const float*)d_in[6];  const float* fb3 = (const float*)d_in[7];
    const float* gW0 = (const float*)d_in[8];  const float* gb0 = (const float*)d_in[9];
    const float* gW1 = (const float*)d_in[10]; const float* gb1 = (const float*)d_in[11];
    const float* gW2 = (const float*)d_in[12]; const float* gb2 = (const float*)d_in[13];
    const float* gW3 = (const float*)d_in[14]; const float* gb3 = (const float*)d_in[15];
    const float* rW  = (const float*)d_in[16]; const float* rb  = (const float*)d_in[17];
    const float* ts  = (const float*)d_in[18]; const float* dbt = (const float*)d_in[19];
    float* out = (float*)d_out;

    // workspace carve (all 16B aligned). Total ~55 MB.
    char* p = (char*)d_ws;
    float* hist  = (float*)p;  p += (size_t)kT * kBH * 4;     // 33.55 MB
    float* drift = (float*)p;  p += (size_t)kBH * 4;          // 0.52 MB
    float* diffb = (float*)p;  p += (size_t)kB * 1024 * 4;    // 8 MB
    float* b0c   = (float*)p;  p += 1024 * 4;
    short* txh   = (short*)p;  p += (size_t)kB * kKP * 2;     // 1.44 MB
    short* b1h   = (short*)p;  p += (size_t)kB * 1024 * 2;    // 4 MB
    short* b2h   = (short*)p;  p += (size_t)kB * 1024 * 2;    // 4 MB
    short* W0t   = (short*)p;  p += (size_t)1024 * kKP * 2;   // 0.72 MB
    short* fW1t  = (short*)p;  p += (size_t)512 * 512 * 2;
    short* gW1t  = (short*)p;  p += (size_t)512 * 512 * 2;
    short* fW2t  = (short*)p;  p += (size_t)512 * 512 * 2;
    short* gW2t  = (short*)p;  p += (size_t)512 * 512 * 2;
    short* fW3t  = (short*)p;  p += (size_t)64 * 512 * 2;
    short* gW3t  = (short*)p;  p += (size_t)1024 * 512 * 2;

    auto tgrid = [](int n) { return dim3((n + 255) / 256); };
    transpose_bf16<<<tgrid(kKP * 512), 256, 0, stream>>>(fW0, W0t, kDIN, 512, kKP, 512);
    transpose_bf16<<<tgrid(kKP * 512), 256, 0, stream>>>(gW0, W0t + (size_t)512 * kKP, kDIN, 512, kKP, 512);
    transpose_bf16<<<tgrid(512 * 512), 256, 0, stream>>>(fW1, fW1t, 512, 512, 512, 512);
    transpose_bf16<<<tgrid(512 * 512), 256, 0, stream>>>(gW1, gW1t, 512, 512, 512, 512);
    transpose_bf16<<<tgrid(512 * 512), 256, 0, stream>>>(fW2, fW2t, 512, 512, 512, 512);
    transpose_bf16<<<tgrid(512 * 512), 256, 0, stream>>>(gW2, gW2t, 512, 512, 512, 512);
    transpose_bf16<<<tgrid(512 * 64), 256, 0, stream>>>(fW3, fW3t, 512, 64, 512, 64);
    transpose_bf16<<<tgrid(512 * 1024), 256, 0, stream>>>(gW3, gW3t, 512, 1024, 512, 1024);
    prep_bias<<<dim3(4), 256, 0, stream>>>(fb0, gb0, b0c);
    init_k<<<dim3(kBH / 256), 256, 0, stream>>>(hist, txh);

    for (int k = 0; k < kT - 1; ++k) {
        step_pre<<<dim3(kBH / 256), 256, 0, stream>>>(hist, drift, diffb, dbt, txh, k);

        MArg l1{txh, W0t, b0c, b1h, nullptr, kKP, kKP, 1024, 0, 1024};
        gemm_mfma<<<dim3(32, 16), 256, 0, stream>>>(l1, l1, 16);

        MArg f2{b1h, fW1t, fb1, b2h, nullptr, 512, 1024, 1024, 0, 512};
        MArg g2{b1h + 512, gW1t, gb1, b2h + 512, nullptr, 512, 1024, 1024, 0, 512};
        gemm_mfma<<<dim3(32, 16), 256, 0, stream>>>(f2, g2, 8);

        MArg f3{b2h, fW2t, fb2, b1h, nullptr, 512, 1024, 1024, 0, 512};
        MArg g3{b2h + 512, gW2t, gb2, b1h + 512, nullptr, 512, 1024, 1024, 0, 512};
        gemm_mfma<<<dim3(32, 16), 256, 0, stream>>>(f3, g3, 8);

        MArg f4{b1h, fW3t, fb3, nullptr, drift, 512, 1024, kH, 1, kH};
        MArg g4{b1h + 512, gW3t, gb3, nullptr, diffb, 512, 1024, 1024, 1, 1024};
        gemm_mfma<<<dim3(32, 17), 256, 0, stream>>>(f4, g4, 1);
    }

    update_k<<<dim3(kBH / 256), 256, 0, stream>>>(hist, drift, diffb, dbt, kT - 2);
    readout_k<<<dim3(kB * kT / 256), 256, 0, stream>>>(hist, rW, rb, ts, out);
}

// Round 4
// 2548.357 us; speedup vs baseline: 4.2257x; 1.1548x over previous
//
#include <hip/hip_runtime.h>
#include <math.h>

// Problem constants
constexpr int kH   = 64;
constexpr int kP   = 4;
constexpr int kN   = 16;
constexpr int kD   = 8;
constexpr int kT   = 64;
constexpr int kWd  = 512;
constexpr int kB   = 2048;
constexpr int kDIN = 1 + kH + kP * kH;  // 321
constexpr int kKP  = 384;               // K padded to multiple of 64
constexpr int kBH  = kB * kH;           // 131072

typedef __attribute__((ext_vector_type(8))) short short8;
typedef __attribute__((ext_vector_type(4))) float f32x4;

// ---- bf16 helpers -----------------------------------------------------------
__device__ __forceinline__ short f2bf(float x) {
    union { float f; unsigned u; } v; v.f = x;
    unsigned r = (v.u + 0x7FFFu + ((v.u >> 16) & 1u)) >> 16;
    return (short)r;
}
__device__ __forceinline__ float bf2f(short h) {
    union { unsigned u; float f; } v; v.u = ((unsigned)(unsigned short)h) << 16;
    return v.f;
}

// ---- async global->LDS 16B --------------------------------------------------
__device__ __forceinline__ void gload16(const short* g, short* l) {
    __builtin_amdgcn_global_load_lds(
        (const __attribute__((address_space(1))) unsigned int*)g,
        (__attribute__((address_space(3))) unsigned int*)l, 16, 0, 0);
}

// ---- weight transpose to bf16 [N][K] with padding ---------------------------
__global__ __launch_bounds__(256) void transpose_bf16(const float* __restrict__ W,
                                                      short* __restrict__ Wt,
                                                      int K, int N, int Kp, int Np) {
    int idx = blockIdx.x * 256 + threadIdx.x;
    if (idx >= Kp * Np) return;
    int n = idx / Kp, kk = idx % Kp;
    float v = (kk < K && n < N) ? W[(size_t)kk * N + n] : 0.f;
    Wt[idx] = f2bf(v);
}

__global__ __launch_bounds__(256) void prep_bias(const float* __restrict__ fb0,
                                                 const float* __restrict__ gb0,
                                                 float* __restrict__ b0c) {
    int i = blockIdx.x * 256 + threadIdx.x;
    if (i < 1024) b0c[i] = (i < kWd) ? fb0[i] : gb0[i - kWd];
}

// ---- init: hist[0]=1, tx pad cols zero --------------------------------------
__global__ __launch_bounds__(256) void init_k(float* __restrict__ hist,
                                              short* __restrict__ txh) {
    int idx = blockIdx.x * 256 + threadIdx.x;
    if (idx < kBH) hist[idx] = 1.0f;
    if (idx < kB * (kKP - kDIN)) {
        int b = idx / (kKP - kDIN), c = idx % (kKP - kDIN);
        txh[(size_t)b * kKP + kDIN + c] = 0;
    }
}

// ---- fused: state update (step k) + build tx features -----------------------
__global__ __launch_bounds__(256) void step_pre(float* __restrict__ hist,
                                                const float* __restrict__ drift,
                                                const short* __restrict__ diffb,
                                                const float* __restrict__ dbt,
                                                short* __restrict__ txh, int k) {
    const int L = k + 1;
    __shared__ float ctab[kT * kP];
    int tid = threadIdx.x;
    float invs = rsqrtf((float)L);
    for (int i = tid; i < L * kP; i += 256) {
        int j = i >> 2, p = i & 3;
        ctab[i] = cosf(6.283185307179586f * (float)(p * j) / (float)L) * invs;
    }
    __syncthreads();
    int idx = blockIdx.x * 256 + tid;
    int b = idx >> 6, h = idx & 63;
    float xk;
    if (k == 0) {
        xk = 1.0f;
    } else {
        xk = hist[(size_t)(k - 1) * kBH + idx] + drift[idx];
        const short* dr = diffb + (size_t)b * 1024 + h * kN;
        const float* wr = dbt + (size_t)(k - 1) * kB * kN + b * kN;
#pragma unroll
        for (int n = 0; n < kN; ++n) xk += bf2f(dr[n]) * wr[n];
        hist[(size_t)k * kBH + idx] = xk;
    }
    const float* hp = hist + (size_t)b * kH + h;
    float a0 = 0.f, a1 = 0.f, a2 = 0.f, a3 = 0.f;
    for (int j = 0; j < k; ++j) {
        float x = hp[(size_t)j * kBH];
        a0 += x * ctab[j * 4 + 0];
        a1 += x * ctab[j * 4 + 1];
        a2 += x * ctab[j * 4 + 2];
        a3 += x * ctab[j * 4 + 3];
    }
    a0 += xk * ctab[k * 4 + 0];
    a1 += xk * ctab[k * 4 + 1];
    a2 += xk * ctab[k * 4 + 2];
    a3 += xk * ctab[k * 4 + 3];
    if (L < 2) a1 = 0.f;
    if (L < 4) a2 = 0.f;
    if (L < 6) a3 = 0.f;
    short* th = txh + (size_t)b * kKP;
    th[1 + kH + 0 * kH + h] = f2bf(a0);
    th[1 + kH + 1 * kH + h] = f2bf(a1);
    th[1 + kH + 2 * kH + h] = f2bf(a2);
    th[1 + kH + 3 * kH + h] = f2bf(a3);
    th[1 + h] = f2bf(xk);
    if (h == 0) th[0] = f2bf((float)k);
}

// ---- MFMA GEMM: C = act(A @ Wt^T + bias) ------------------------------------
// 256 threads = 4 waves (2M x 2N), block tile 64x64, wave tile 32x32.
// BK=64 as two 32-col panels; double-buffered; ONE __syncthreads per K-tile
// (its vmcnt(0) drains the prefetch issued last iteration -> loads overlap
// compute). LDS XOR-swizzle (slot ^= (row>>1)&3) on global source + read index
// (linear LDS dest for global_load_lds) -> 2-way bank conflicts (free).
struct MArg {
    const short* A;                     // [2048 x lda] bf16
    const short* Bt;                    // [Np x K] bf16 (transposed weights)
    const float* bias;
    short* Cb;                          // bf16 out (act0: relu, act1: tanh)
    float* Cf;                          // fp32 out (act1, when Cb==nullptr)
    int K, lda, ldc, act, Nw;
};

__global__ __launch_bounds__(256, 2) void gemm_mfma(MArg f, MArg g, int ysplit) {
    const int y = blockIdx.y;
    MArg a;
    int n0;
    if (y < ysplit) { a = f; n0 = y * 64; }
    else            { a = g; n0 = (y - ysplit) * 64; }
    const int m0 = blockIdx.x * 64;

    __shared__ __align__(16) short sA[2][2][64 * 32];
    __shared__ __align__(16) short sB[2][2][64 * 32];

    const int tid = threadIdx.x;
    const int lane = tid & 63;
    const int w = tid >> 6;
    const int wm = (w & 1) * 32;
    const int wn = (w >> 1) * 32;

    const int sr = tid >> 2;                       // staging row 0..63
    const int s  = tid & 3;                        // 16B slot in 32-col panel
    const int scol = (s ^ ((sr >> 1) & 3)) * 8;    // inverse-swizzled source col
    const int sdst = sr * 32 + s * 8;              // linear LDS dest (elems)

    const short* gA = a.A  + (size_t)(m0 + sr) * a.lda + scol;
    const short* gB = a.Bt + (size_t)(n0 + sr) * a.K   + scol;

    const int nk = a.K >> 6;
    f32x4 acc[2][2] = {};

    // prologue: stage K-tile 0 into buffer 0
    gload16(gA,      &sA[0][0][sdst]);
    gload16(gA + 32, &sA[0][1][sdst]);
    gload16(gB,      &sB[0][0][sdst]);
    gload16(gB + 32, &sB[0][1][sdst]);

    const int fr = lane & 15;
    const int kb = ((lane >> 4) ^ ((fr >> 1) & 3)) * 8;  // swizzled read col
    const int ra0 = (wm + fr) * 32 + kb, ra1 = (wm + 16 + fr) * 32 + kb;
    const int rb0 = (wn + fr) * 32 + kb, rb1 = (wn + 16 + fr) * 32 + kb;

    for (int kt = 0; kt < nk; ++kt) {
        __syncthreads();  // joins + vmcnt(0): buf[kt&1] staged, prev reads done
        const int cur = kt & 1, nxt = cur ^ 1;
        if (kt + 1 < nk) {
            const int ko = (kt + 1) << 6;
            gload16(gA + ko,      &sA[nxt][0][sdst]);
            gload16(gA + ko + 32, &sA[nxt][1][sdst]);
            gload16(gB + ko,      &sB[nxt][0][sdst]);
            gload16(gB + ko + 32, &sB[nxt][1][sdst]);
        }
#pragma unroll
        for (int ks = 0; ks < 2; ++ks) {
            short8 a0 = *(const short8*)&sA[cur][ks][ra0];
            short8 a1 = *(const short8*)&sA[cur][ks][ra1];
            short8 b0 = *(const short8*)&sB[cur][ks][rb0];
            short8 b1 = *(const short8*)&sB[cur][ks][rb1];
            acc[0][0] = __builtin_amdgcn_mfma_f32_16x16x32_bf16(a0, b0, acc[0][0], 0, 0, 0);
            acc[0][1] = __builtin_amdgcn_mfma_f32_16x16x32_bf16(a0, b1, acc[0][1], 0, 0, 0);
            acc[1][0] = __builtin_amdgcn_mfma_f32_16x16x32_bf16(a1, b0, acc[1][0], 0, 0, 0);
            acc[1][1] = __builtin_amdgcn_mfma_f32_16x16x32_bf16(a1, b1, acc[1][1], 0, 0, 0);
        }
    }

    const int rq = (lane >> 4) * 4;
#pragma unroll
    for (int j = 0; j < 2; ++j) {
        int n = n0 + wn + j * 16 + fr;
        if (n >= a.Nw) continue;
        float bias = a.bias[n];
#pragma unroll
        for (int i = 0; i < 2; ++i) {
#pragma unroll
            for (int r = 0; r < 4; ++r) {
                int m = m0 + wm + i * 16 + rq + r;
                float v = acc[i][j][r] + bias;
                if (a.act == 0) {
                    a.Cb[(size_t)m * a.ldc + n] = f2bf(fmaxf(v, 0.f));
                } else if (a.Cb) {
                    a.Cb[(size_t)m * a.ldc + n] = f2bf(tanhf(v));
                } else {
                    a.Cf[(size_t)m * a.ldc + n] = tanhf(v);
                }
            }
        }
    }
}

// ---- final state update (k = T-1) -------------------------------------------
__global__ __launch_bounds__(256) void update_k(float* __restrict__ hist,
                                                const float* __restrict__ drift,
                                                const short* __restrict__ diffb,
                                                const float* __restrict__ dbt, int k) {
    int idx = blockIdx.x * 256 + threadIdx.x;
    int b = idx >> 6, h = idx & 63;
    float s = hist[(size_t)k * kBH + idx] + drift[idx];
    const short* dr = diffb + (size_t)b * 1024 + h * kN;
    const float* wr = dbt + (size_t)k * kB * kN + b * kN;
#pragma unroll
    for (int n = 0; n < kN; ++n) s += bf2f(dr[n]) * wr[n];
    hist[(size_t)(k + 1) * kBH + idx] = s;
}

// ---- readout ----------------------------------------------------------------
__global__ __launch_bounds__(256) void readout_k(const float* __restrict__ hist,
                                                 const float* __restrict__ rW,
                                                 const float* __restrict__ rb,
                                                 const float* __restrict__ ts,
                                                 float* __restrict__ out) {
    __shared__ float sW[kH * kD];
    __shared__ float sb[kD];
    __shared__ float sts[kT];
    int tid = threadIdx.x;
    sW[tid] = rW[tid];
    sW[tid + 256] = rW[tid + 256];
    if (tid < kD) sb[tid] = rb[tid];
    if (tid < kT) sts[tid] = ts[tid];
    __syncthreads();
    int idx = blockIdx.x * 256 + tid;
    int t = idx & (kT - 1), b = idx >> 6;
    const float* xr = hist + (size_t)t * kBH + (size_t)b * kH;
    float acc[kD];
#pragma unroll
    for (int d = 0; d < kD; ++d) acc[d] = sb[d];
    for (int h = 0; h < kH; ++h) {
        float x = xr[h];
#pragma unroll
        for (int d = 0; d < kD; ++d) acc[d] += x * sW[h * kD + d];
    }
    float* o = out + (size_t)((size_t)b * kT + t) * (1 + kD);
    o[0] = sts[t];
#pragma unroll
    for (int d = 0; d < kD; ++d) o[1 + d] = acc[d];
}

extern "C" void kernel_launch(void* const* d_in, const int* in_sizes, int n_in,
                              void* d_out, int out_size, void* d_ws, size_t ws_size,
                              hipStream_t stream) {
    const float* fW0 = (const float*)d_in[0];  const float* fb0 = (const float*)d_in[1];
    const float* fW1 = (const float*)d_in[2];  const float* fb1 = (const float*)d_in[3];
    const float* fW2 = (const float*)d_in[4];  const float* fb2 = (const float*)d_in[5];
    const float* fW3 = (const float*)d_in[6];  const float* fb3 = (const float*)d_in[7];
    const float* gW0 = (const float*)d_in[8];  const float* gb0 = (const float*)d_in[9];
    const float* gW1 = (const float*)d_in[10]; const float* gb1 = (const float*)d_in[11];
    const float* gW2 = (const float*)d_in[12]; const float* gb2 = (const float*)d_in[13];
    const float* gW3 = (const float*)d_in[14]; const float* gb3 = (const float*)d_in[15];
    const float* rW  = (const float*)d_in[16]; const float* rb  = (const float*)d_in[17];
    const float* ts  = (const float*)d_in[18]; const float* dbt = (const float*)d_in[19];
    float* out = (float*)d_out;

    // workspace carve (all 16B aligned). Total ~50 MB.
    char* p = (char*)d_ws;
    float* hist  = (float*)p;  p += (size_t)kT * kBH * 4;     // 33.55 MB
    float* drift = (float*)p;  p += (size_t)kBH * 4;          // 0.52 MB
    float* b0c   = (float*)p;  p += 1024 * 4;
    short* diffb = (short*)p;  p += (size_t)kB * 1024 * 2;    // 4 MB (bf16)
    short* txh   = (short*)p;  p += (size_t)kB * kKP * 2;     // 1.5 MB
    short* b1h   = (short*)p;  p += (size_t)kB * 1024 * 2;    // 4 MB
    short* b2h   = (short*)p;  p += (size_t)kB * 1024 * 2;    // 4 MB
    short* W0t   = (short*)p;  p += (size_t)1024 * kKP * 2;   // 0.75 MB
    short* fW1t  = (short*)p;  p += (size_t)512 * 512 * 2;
    short* gW1t  = (short*)p;  p += (size_t)512 * 512 * 2;
    short* fW2t  = (short*)p;  p += (size_t)512 * 512 * 2;
    short* gW2t  = (short*)p;  p += (size_t)512 * 512 * 2;
    short* fW3t  = (short*)p;  p += (size_t)64 * 512 * 2;
    short* gW3t  = (short*)p;  p += (size_t)1024 * 512 * 2;

    auto tgrid = [](int n) { return dim3((n + 255) / 256); };
    transpose_bf16<<<tgrid(kKP * 512), 256, 0, stream>>>(fW0, W0t, kDIN, 512, kKP, 512);
    transpose_bf16<<<tgrid(kKP * 512), 256, 0, stream>>>(gW0, W0t + (size_t)512 * kKP, kDIN, 512, kKP, 512);
    transpose_bf16<<<tgrid(512 * 512), 256, 0, stream>>>(fW1, fW1t, 512, 512, 512, 512);
    transpose_bf16<<<tgrid(512 * 512), 256, 0, stream>>>(gW1, gW1t, 512, 512, 512, 512);
    transpose_bf16<<<tgrid(512 * 512), 256, 0, stream>>>(fW2, fW2t, 512, 512, 512, 512);
    transpose_bf16<<<tgrid(512 * 512), 256, 0, stream>>>(gW2, gW2t, 512, 512, 512, 512);
    transpose_bf16<<<tgrid(512 * 64), 256, 0, stream>>>(fW3, fW3t, 512, 64, 512, 64);
    transpose_bf16<<<tgrid(512 * 1024), 256, 0, stream>>>(gW3, gW3t, 512, 1024, 512, 1024);
    prep_bias<<<dim3(4), 256, 0, stream>>>(fb0, gb0, b0c);
    init_k<<<dim3(kBH / 256), 256, 0, stream>>>(hist, txh);

    for (int k = 0; k < kT - 1; ++k) {
        step_pre<<<dim3(kBH / 256), 256, 0, stream>>>(hist, drift, diffb, dbt, txh, k);

        MArg l1{txh, W0t, b0c, b1h, nullptr, kKP, kKP, 1024, 0, 1024};
        gemm_mfma<<<dim3(32, 16), 256, 0, stream>>>(l1, l1, 16);

        MArg f2{b1h, fW1t, fb1, b2h, nullptr, 512, 1024, 1024, 0, 512};
        MArg g2{b1h + 512, gW1t, gb1, b2h + 512, nullptr, 512, 1024, 1024, 0, 512};
        gemm_mfma<<<dim3(32, 16), 256, 0, stream>>>(f2, g2, 8);

        MArg f3{b2h, fW2t, fb2, b1h, nullptr, 512, 1024, 1024, 0, 512};
        MArg g3{b2h + 512, gW2t, gb2, b1h + 512, nullptr, 512, 1024, 1024, 0, 512};
        gemm_mfma<<<dim3(32, 16), 256, 0, stream>>>(f3, g3, 8);

        MArg f4{b1h, fW3t, fb3, nullptr, drift, 512, 1024, kH, 1, kH};
        MArg g4{b1h + 512, gW3t, gb3, diffb, nullptr, 512, 1024, 1024, 1, 1024};
        gemm_mfma<<<dim3(32, 17), 256, 0, stream>>>(f4, g4, 1);
    }

    update_k<<<dim3(kBH / 256), 256, 0, stream>>>(hist, drift, diffb, dbt, kT - 2);
    readout_k<<<dim3(kB * kT / 256), 256, 0, stream>>>(hist, rW, rb, ts, out);
}